// Round 7
// baseline (265.542 us; speedup 1.0000x reference)
//
#include <hip/hip_runtime.h>

// ---------------- bf16 helpers (raw ushort storage) ----------------
__device__ __forceinline__ float b2f(unsigned short u) {
    union { unsigned int i; float f; } x; x.i = ((unsigned int)u) << 16; return x.f;
}
__device__ __forceinline__ unsigned short f2b(float f) {
    union { float f; unsigned int i; } x; x.f = f;
    unsigned int r = x.i + 0x7fffu + ((x.i >> 16) & 1u);   // RNE
    return (unsigned short)(r >> 16);
}
__device__ __forceinline__ bool finitef(float x) {
    union { float f; unsigned int u; } c; c.f = x;
    return ((c.u >> 23) & 0xffu) != 0xffu;
}

typedef __attribute__((ext_vector_type(8))) __bf16 bf16x8;
typedef __attribute__((ext_vector_type(4))) float f32x4;

#define HDIM 128
#define LSTR 136
// Fused adjacency row: one 128B cache line per node = [int cnt | 62 x ushort adj].
#define ROWU 64    // ushorts per row (128B)
#define DCAP 62    // adjacency capacity
// BN stats shadow copies (32x less atomic contention; consumers sum copies).
#define NCOPY 32
// R2 lesson: 64B-granularity gathers regress (sub-line random requests).
// R3 lesson: scatter WRITE amplification = memory-side RMW of 800k device atomics
//            -> two-phase binned CSR build (R5: confirmed win).
// R6 lesson: more wave-level MLP does NOT help agg (latency x outstanding-request
//            capacity saturated); only L2-MISS REDUCTION can. R7: split activations
//            into two [N][64] halves (row = one full 128B line), pin half to an XCD
//            quad -> per-XCD random working set 12.8MB -> 6.4MB.
#define NB 256      // dst-range buckets
#define BCAP 8192   // edges per bucket capacity (mean E/NB ~ 3.1k; binomial tail ~0)

// BN scale/shift from per-column shadow-copy sums (computed redundantly per consumer block)
__device__ __forceinline__ void bn_compute(const float* colsum, const float* colsq,
                                           const unsigned short* gam, const unsigned short* bet,
                                           int isbf, float invn, int f,
                                           float* sc_out, float* sf_out) {
    float cs = 0.f, cq = 0.f;
#pragma unroll
    for (int c = 0; c < NCOPY; ++c) {
        cs += colsum[c * 128 + f];
        cq += colsq[c * 128 + f];
    }
    float gv, bv;
    if (isbf) { gv = b2f(gam[f]);            bv = b2f(bet[f]); }
    else      { gv = ((const float*)gam)[f]; bv = ((const float*)bet)[f]; }
    if (!finitef(cs) || !finitef(cq)) { *sc_out = 0.f; *sf_out = 150.f; return; }
    float mu = cs * invn;
    float var = cq * invn - mu * mu;
    var = var < 0.f ? 0.f : var;
    float rstd = rsqrtf(var + 1e-5f);
    float s = gv * rstd;
    *sc_out = s;
    *sf_out = bv - mu * s;
}

// ---------------- failure-path fill ----------------
__global__ void fill_f32(float* p, int n, float v) {
    int i = blockIdx.x * 256 + threadIdx.x;
    if (i < n) p[i] = v;
}

// ---------------- prep: dtype+is64 detect, W transpose, zero stats+bucketCnt ----------------
__global__ void prep(const unsigned short* __restrict__ X0, const int* __restrict__ ei,
                     const unsigned short* __restrict__ W1, const unsigned short* __restrict__ W2,
                     unsigned short* __restrict__ Wt1, unsigned short* __restrict__ Wt2,
                     int* __restrict__ zbase, int zcount, int* __restrict__ flags) {
    int bid = blockIdx.x, tid = threadIdx.x;
    if (bid < 128) {
        __shared__ int sane, hi64;
        if (tid == 0) { sane = 0; hi64 = 0; }
        __syncthreads();
        unsigned short u = X0[2 * tid];
        int e = (u >> 7) & 0xff;
        if (e >= 100 && e <= 140) atomicAdd(&sane, 1);
        if (bid == 0 && tid < 64) {          // int64 edges => high words all zero
            if (ei[2 * tid + 1] != 0) atomicAdd(&hi64, 1);
        }
        __syncthreads();
        int isbf = (sane >= 128) ? 1 : 0;
        if (bid == 0 && tid == 0) { flags[0] = isbf; flags[1] = (hi64 == 0) ? 1 : 0; }
        int idx = bid * 256 + tid;           // 0..32767
        const unsigned short* src; unsigned short* dst; int l;
        if (idx < 16384) { src = W1; dst = Wt1; l = idx; }
        else             { src = W2; dst = Wt2; l = idx - 16384; }
        int k = l >> 7, c = l & 127;
        unsigned short v = isbf ? src[l] : f2b(((const float*)src)[l]);
        dst[c * 128 + k] = v;                // Wt[n][k]
    } else {
        int i = (bid - 128) * 256 + tid;
        if (i < zcount) zbase[i] = 0;
    }
}

// ---------------- Phase A: bin edges by dst range, aggregated slot-claims ----------------
__global__ __launch_bounds__(256) void bin_edges(const int* __restrict__ ei,
                                                 unsigned int* __restrict__ bData,
                                                 unsigned int* __restrict__ bCnt,
                                                 const int* __restrict__ flags,
                                                 int E, int N, int BSZ) {
    __shared__ unsigned int cnt[NB];
    __shared__ unsigned int base[NB];
    int tid = threadIdx.x;
    int is64 = flags[1];
    int e0 = blockIdx.x * 4096;
    cnt[tid] = 0;                            // blockDim == NB == 256
    __syncthreads();
    unsigned int val[16], loff[16]; int bk[16];
#pragma unroll
    for (int j = 0; j < 16; ++j) {
        int e = e0 + j * 256 + tid;
        bk[j] = -1;
        if (e < E) {
            int d, s;
            if (is64) { d = ei[2 * (size_t)E + 2 * (size_t)e]; s = ei[2 * (size_t)e]; }
            else      { d = ei[(size_t)E + e];                 s = ei[e]; }
            d = d < 0 ? 0 : (d >= N ? N - 1 : d);
            s = s < 0 ? 0 : (s >= N ? N - 1 : s);
            int b = d / BSZ;
            int loc = d - b * BSZ;           // < BSZ <= 256
            val[j] = (unsigned int)s | ((unsigned int)loc << 16);
            bk[j] = b;
            loff[j] = atomicAdd(&cnt[b], 1u);
        }
    }
    __syncthreads();
    unsigned int c = cnt[tid];
    base[tid] = (c > 0) ? atomicAdd(&bCnt[tid], c) : 0u;   // bucket tid
    __syncthreads();
#pragma unroll
    for (int j = 0; j < 16; ++j) {
        if (bk[j] >= 0) {
            unsigned int pos = base[bk[j]] + loff[j];
            if (pos < BCAP) bData[(size_t)bk[j] * BCAP + pos] = val[j];
        }
    }
}

// ---------------- Phase B: build csr rows in LDS, stream out full lines ----------------
__global__ __launch_bounds__(256) void build_csr(const unsigned int* __restrict__ bData,
                                                 const unsigned int* __restrict__ bCnt,
                                                 unsigned short* __restrict__ csr2d,
                                                 int N, int BSZ) {
    __shared__ __align__(16) unsigned short rows[256 * ROWU];   // 32KB
    int b = blockIdx.x;
    int tid = threadIdx.x;
    int node0 = b * BSZ;
    int nn = N - node0; if (nn > BSZ) nn = BSZ;
    if (nn <= 0) return;
    uint4* r4 = (uint4*)rows;
#pragma unroll
    for (int i = 0; i < 8; ++i) { uint4 z = {0u, 0u, 0u, 0u}; r4[tid + i * 256] = z; }
    __syncthreads();
    unsigned int ne = bCnt[b]; if (ne > BCAP) ne = BCAP;
    const unsigned int* bd = &bData[(size_t)b * BCAP];
    for (unsigned int t = tid; t < ne; t += 256) {
        unsigned int v = bd[t];
        unsigned int loc = v >> 16;
        unsigned int s = v & 0xffffu;
        unsigned int c = atomicAdd((unsigned int*)&rows[loc * ROWU], 1u);
        if (c < DCAP) rows[loc * ROWU + 2 + c] = (unsigned short)s;
    }
    __syncthreads();
    uint4* g4 = (uint4*)&csr2d[(size_t)node0 * ROWU];
    int tot = nn * (ROWU / 8);
    for (int i = tid; i < tot; i += 256) g4[i] = r4[i];
}

// ---------------- GEMM (MFMA 16x16x32 bf16): C halves [2][n][64] = dinv*(A@W) ----------------
// mode != 2: A node-major external input (fp32/bf16). mode == 2: A = AGG halves
// [2][n][64] with fused BN+ReLU staging. C output ALWAYS split into [2][n][64].
__global__ __launch_bounds__(256) void gemm_mfma(
    const unsigned short* __restrict__ A, const unsigned short* __restrict__ Wt,
    unsigned short* __restrict__ C, const int* __restrict__ aflag, int mode,
    const float* __restrict__ colsum, const float* __restrict__ colsq,
    const unsigned short* __restrict__ gam, const unsigned short* __restrict__ bet,
    float invn, const unsigned short* __restrict__ csr2d, int n) {
    __shared__ __align__(16) unsigned short Wl[128 * LSTR];
    __shared__ __align__(16) unsigned short Al[64 * LSTR];
    __shared__ float sc_sh[128], sf_sh[128];
    int tid = threadIdx.x;
    int row0 = blockIdx.x * 64;
    int isbf = aflag[0];
    size_t cs = (size_t)n * 64;          // half stride (ushorts)

    if (mode == 2 && tid < 128)
        bn_compute(colsum, colsq, gam, bet, isbf, invn, tid, &sc_sh[tid], &sf_sh[tid]);

    const uint4* Wg = (const uint4*)Wt;
#pragma unroll
    for (int it = 0; it < 8; ++it) {
        int idx = tid + it * 256;
        int nn = idx >> 4, k8 = idx & 15;
        *(uint4*)&Wl[nn * LSTR + k8 * 8] = Wg[idx];
    }
    if (mode == 2) __syncthreads();   // sc_sh/sf_sh ready before A staging

    int amode = (mode == 2) ? 2 : isbf;
    if (amode == 1) {
        const uint4* Ag = (const uint4*)A;
        for (int it = 0; it < 4; ++it) {
            int idx = tid + it * 256;
            int r = idx >> 4, cc = idx & 15;
            int gr = row0 + r;
            uint4 v; v.x = v.y = v.z = v.w = 0u;
            if (gr < n) v = Ag[(size_t)gr * 16 + cc];
            *(uint4*)&Al[r * LSTR + cc * 8] = v;
        }
    } else if (amode == 0) {
        const uint4* Af = (const uint4*)A;
        for (int it = 0; it < 8; ++it) {
            int idx = tid + it * 256;
            int r = idx >> 5, c4 = idx & 31;
            int gr = row0 + r;
            uint4 v; v.x = v.y = v.z = v.w = 0u;
            if (gr < n) v = Af[(size_t)gr * 32 + c4];
            float ff[4]; *(uint4*)ff = v;
            ushort4 o;
            o.x = f2b(ff[0]); o.y = f2b(ff[1]); o.z = f2b(ff[2]); o.w = f2b(ff[3]);
            *(ushort4*)&Al[r * LSTR + c4 * 4] = o;
        }
    } else {                   // AGG halves bf16 + fused BN + ReLU (from sc_sh/sf_sh)
        const uint4* Ag = (const uint4*)A;
        size_t cs4 = (size_t)n * 8;      // half stride in uint4
        for (int it = 0; it < 4; ++it) {
            int idx = tid + it * 256;
            int r = idx >> 4, cc = idx & 15;
            int gr = row0 + r;
            uint4 v; v.x = v.y = v.z = v.w = 0u;
            if (gr < n) v = Ag[(size_t)(cc >> 3) * cs4 + (size_t)gr * 8 + (cc & 7)];
            unsigned short hu[8]; *(uint4*)hu = v;
            unsigned short ou[8];
#pragma unroll
            for (int j = 0; j < 8; ++j) {
                int f = cc * 8 + j;
                float x = b2f(hu[j]) * sc_sh[f] + sf_sh[f];
                ou[j] = f2b(x > 0.f ? x : 0.f);
            }
            *(uint4*)&Al[r * LSTR + cc * 8] = *(uint4*)ou;
        }
    }
    __syncthreads();

    int wave = tid >> 6, lane = tid & 63;
    int m = lane & 15, quad = lane >> 4;

    bf16x8 afr[4];
#pragma unroll
    for (int kc = 0; kc < 4; ++kc)
        afr[kc] = *(const bf16x8*)&Al[(wave * 16 + m) * LSTR + kc * 32 + quad * 8];

    float dv[4];
#pragma unroll
    for (int i2 = 0; i2 < 4; ++i2) {
        int gr = row0 + wave * 16 + quad * 4 + i2;
        if (gr < n) {
            int ct = *(const int*)&csr2d[(size_t)gr * ROWU];
            dv[i2] = rsqrtf((float)ct + 1.0f);
        } else dv[i2] = 0.f;
    }

    for (int t = 0; t < 8; ++t) {
        f32x4 acc = {0.f, 0.f, 0.f, 0.f};
#pragma unroll
        for (int kc = 0; kc < 4; ++kc) {
            bf16x8 bfr = *(const bf16x8*)&Wl[(t * 16 + m) * LSTR + kc * 32 + quad * 8];
            acc = __builtin_amdgcn_mfma_f32_16x16x32_bf16(afr[kc], bfr, acc, 0, 0, 0);
        }
        unsigned short* Cb = C + (size_t)(t >> 2) * cs;      // feature half
        int fl = (t & 3) * 16 + m;                           // local feature 0..63
#pragma unroll
        for (int i2 = 0; i2 < 4; ++i2) {
            int gr = row0 + wave * 16 + quad * 4 + i2;
            if (gr < n) Cb[(size_t)gr * 64 + fl] = f2b(acc[i2] * dv[i2]);
        }
    }
}

// ---------------- aggregation + fused BN column stats (XCD-pinned feature halves) ------
// Gather row = ONE 128B line (R2's 64B mistake avoided). half = (bid&7)>>2 pins each
// 6.4MB activation half to an XCD quad -> per-XCD random working set halves.
// Wave: 8 groups x 8 lanes; 8 gather rows in flight per iteration at R5's VGPR cost.
__global__ __launch_bounds__(256) void agg_stats(
    const unsigned short* __restrict__ Hb, const unsigned short* __restrict__ csr2d,
    unsigned short* __restrict__ AGG,
    float* __restrict__ colsum, float* __restrict__ colsq, int n) {
    int tid = threadIdx.x;
    int bid = blockIdx.x;
    int wave = tid >> 6, lane = tid & 63;
    int g = lane >> 3, q = lane & 7;          // group 0..7, lane covers features q*8..q*8+7
    int xcd = bid & 7;
    int half = xcd >> 2;
    int sb = (bid >> 3) * 4 + (xcd & 3);      // sub-block within half
    int gid = sb * 4 + wave;
    int ngrp = (gridDim.x >> 3) * 16;         // wave-groups per half
    const unsigned short* Hh = Hb + (size_t)half * (size_t)n * 64;
    unsigned short* Ah = AGG + (size_t)half * (size_t)n * 64;

    float s1[8], s2[8];
#pragma unroll
    for (int j = 0; j < 8; ++j) { s1[j] = 0.f; s2[j] = 0.f; }

    for (int i = gid; i < n; i += ngrp) {
        const unsigned short* row = &csr2d[(size_t)i * ROWU];
        int ct = *(const int*)row;            // broadcast line (includes adj)
        float di = rsqrtf((float)ct + 1.0f);
        int c = ct < DCAP ? ct : DCAP;
        const unsigned short* adj = row + 2;
        float acc[8];
#pragma unroll
        for (int j = 0; j < 8; ++j) acc[j] = 0.f;

        if (g == 0) {   // self-loop (pre-scaled row): 8 lanes x 16B = the full line
            uint4 a4 = *(const uint4*)&Hh[(size_t)i * 64 + q * 8];
            unsigned short au[8]; *(uint4*)au = a4;
#pragma unroll
            for (int j = 0; j < 8; ++j) acc[j] += b2f(au[j]);
        }

        int t = g;
        for (; t + 8 < c; t += 16) {          // 2-deep chain x 8 groups = 16 rows in flight
            int sA = adj[t];
            int sB = adj[t + 8];
            uint4 a4 = *(const uint4*)&Hh[(size_t)sA * 64 + q * 8];
            uint4 b4 = *(const uint4*)&Hh[(size_t)sB * 64 + q * 8];
            unsigned short au[8]; *(uint4*)au = a4;
            unsigned short bu[8]; *(uint4*)bu = b4;
#pragma unroll
            for (int j = 0; j < 8; ++j) acc[j] += b2f(au[j]) + b2f(bu[j]);
        }
        for (; t < c; t += 8) {
            int sA = adj[t];
            uint4 a4 = *(const uint4*)&Hh[(size_t)sA * 64 + q * 8];
            unsigned short au[8]; *(uint4*)au = a4;
#pragma unroll
            for (int j = 0; j < 8; ++j) acc[j] += b2f(au[j]);
        }

#pragma unroll
        for (int j = 0; j < 8; ++j) {         // sum over the 8 groups (lane bits 3..5)
            acc[j] += __shfl_xor(acc[j], 8, 64);
            acc[j] += __shfl_xor(acc[j], 16, 64);
            acc[j] += __shfl_xor(acc[j], 32, 64);
            acc[j] *= di;
        }
        if (g == 0) {
            unsigned short ou[8];
#pragma unroll
            for (int j = 0; j < 8; ++j) {
                float v = acc[j];
                ou[j] = f2b(v);
                s1[j] += v; s2[j] += v * v;
            }
            *(uint4*)&Ah[(size_t)i * 64 + q * 8] = *(uint4*)ou;   // full-line write
        }
    }

    __shared__ float sh[4][128];
    if (g == 0) {
#pragma unroll
        for (int j = 0; j < 8; ++j) {
            sh[wave][q * 8 + j] = s1[j];
            sh[wave][64 + q * 8 + j] = s2[j];
        }
    }
    __syncthreads();
    if (tid < 128) {
        float a = sh[0][tid] + sh[1][tid] + sh[2][tid] + sh[3][tid];
        int copy = bid & (NCOPY - 1);
        if (tid < 64) atomicAdd(&colsum[copy * 128 + half * 64 + tid], a);
        else          atomicAdd(&colsq[copy * 128 + half * 64 + (tid - 64)], a);
    }
}

// ---------------- final: compute BN per-block + apply + ReLU to fp32 d_out ----------------
__global__ void bn_apply_f32(const unsigned short* __restrict__ AGG,
                             const float* __restrict__ colsum, const float* __restrict__ colsq,
                             const unsigned short* __restrict__ gam, const unsigned short* __restrict__ bet,
                             const int* __restrict__ flag, float invn,
                             float* __restrict__ out, int nchunk, int n) {
    __shared__ float sc_sh[128], sf_sh[128];
    int tid = threadIdx.x;
    if (tid < 128)
        bn_compute(colsum, colsq, gam, bet, flag[0], invn, tid, &sc_sh[tid], &sf_sh[tid]);
    __syncthreads();
    int i = blockIdx.x * 256 + tid;
    if (i >= nchunk) return;
    int base = i * 8;
    int node = base >> 7;
    int f0 = base & 127;
    size_t cs = (size_t)n * 64;
    uint4 hv = *(const uint4*)&AGG[(size_t)(f0 >> 6) * cs + (size_t)node * 64 + (f0 & 63)];
    unsigned short hu[8]; *(uint4*)hu = hv;
    float o[8];
#pragma unroll
    for (int j = 0; j < 8; ++j) {
        float v = b2f(hu[j]) * sc_sh[f0 + j] + sf_sh[f0 + j];
        o[j] = v > 0.f ? v : 0.f;
    }
    *(float4*)&out[base] = *(float4*)&o[0];
    *(float4*)&out[base + 4] = *(float4*)&o[4];
}

// ---------------- launch ----------------
extern "C" void kernel_launch(void* const* d_in, const int* in_sizes, int n_in,
                              void* d_out, int out_size, void* d_ws, size_t ws_size,
                              hipStream_t stream) {
    const unsigned short* X0 = (const unsigned short*)d_in[0];
    const int* ei = (const int*)d_in[1];
    const unsigned short* W1 = (const unsigned short*)d_in[2];
    const unsigned short* W2 = (const unsigned short*)d_in[4];
    const unsigned short* g1 = (const unsigned short*)d_in[6];
    const unsigned short* be1 = (const unsigned short*)d_in[7];
    const unsigned short* g2 = (const unsigned short*)d_in[8];
    const unsigned short* be2 = (const unsigned short*)d_in[9];
    float* OUT = (float*)d_out;

    int N = in_sizes[0] / HDIM;
    int E = in_sizes[1] / 2;
    int total = N * HDIM;
    int applyb = (total + 255) / 256;

    bool ok = (n_in == 10) && (N > 0) && (in_sizes[0] == N * HDIM) && (E > 0)
           && (in_sizes[2] == HDIM * HDIM) && (in_sizes[4] == HDIM * HDIM)
           && (in_sizes[6] == HDIM) && (in_sizes[9] == HDIM) && (out_size == total)
           && (N <= 65536);
    if (!ok) { fill_f32<<<applyb, 256, 0, stream>>>(OUT, total, -100.0f); return; }

    size_t need = 1024 + (size_t)N * ROWU * 2 + (size_t)NCOPY * 512 * 4 + NB * 4 + 64
                + (size_t)total * 4 + 65536 + (size_t)NB * BCAP * 4 + 4096;
    if (ws_size < need) { fill_f32<<<applyb, 256, 0, stream>>>(OUT, total, -300.0f); return; }

    char* w = (char*)d_ws;
    w = (char*)(((uintptr_t)w + 255) & ~(uintptr_t)255);
    unsigned short* csr2d = (unsigned short*)w; w += (size_t)N * ROWU * 2;
    float* stats = (float*)w; w += (size_t)NCOPY * 512 * 4;  // [zero region start]
    unsigned int* bCnt = (unsigned int*)w; w += NB * 4;      // [zero region end]
    int* flags = (int*)w;     w += 64;                       // written by prep (NOT zeroed)
    w = (char*)(((uintptr_t)w + 255) & ~(uintptr_t)255);
    unsigned short* Hb = (unsigned short*)w;  w += (size_t)total * 2;   // halves [2][N][64]
    unsigned short* AGG = (unsigned short*)w; w += (size_t)total * 2;   // halves [2][N][64]
    unsigned short* Wt1 = (unsigned short*)w; w += (size_t)HDIM * HDIM * 2;
    unsigned short* Wt2 = (unsigned short*)w; w += (size_t)HDIM * HDIM * 2;
    w = (char*)(((uintptr_t)w + 255) & ~(uintptr_t)255);
    unsigned int* bData = (unsigned int*)w; w += (size_t)NB * BCAP * 4;

    float* colsum1 = stats;
    float* colsq1 = stats + NCOPY * 128;
    float* colsum2 = stats + 2 * NCOPY * 128;
    float* colsq2 = stats + 3 * NCOPY * 128;

    int gemmb = (N + 63) / 64;
    float invn = 1.0f / (float)N;
    int BSZ = (N + NB - 1) / NB;                        // <= 256 given N <= 65536
    int zcount = NCOPY * 512 + NB;                      // stats floats + bucket counts

    prep<<<128 + (zcount + 255) / 256, 256, 0, stream>>>(X0, ei, W1, W2, Wt1, Wt2,
                                                         (int*)stats, zcount, flags);
    bin_edges<<<(E + 4095) / 4096, 256, 0, stream>>>(ei, bData, bCnt, flags, E, N, BSZ);
    build_csr<<<NB, 256, 0, stream>>>(bData, bCnt, csr2d, N, BSZ);

    // layer 1: Hb = dinv * (X @ W1)   (split halves output)
    gemm_mfma<<<gemmb, 256, 0, stream>>>(X0, Wt1, Hb, flags, -1,
                                         nullptr, nullptr, nullptr, nullptr, invn, csr2d, N);
    agg_stats<<<2048, 256, 0, stream>>>(Hb, csr2d, AGG, colsum1, colsq1, N);

    // layer 2: BN(L1) + ReLU fused into gemm A-staging (BN computed per-block from colsum1)
    gemm_mfma<<<gemmb, 256, 0, stream>>>(AGG, Wt2, Hb, flags, 2,
                                         colsum1, colsq1, g1, be1, invn, csr2d, N);
    agg_stats<<<2048, 256, 0, stream>>>(Hb, csr2d, AGG, colsum2, colsq2, N);

    // final BN+ReLU (BN computed per-block from colsum2)
    bn_apply_f32<<<(total / 8 + 255) / 256, 256, 0, stream>>>(AGG, colsum2, colsq2,
                                                              g2, be2, flags, invn, OUT, total / 8, N);
}

// Round 14
// 238.535 us; speedup vs baseline: 1.1132x; 1.1132x over previous
//
#include <hip/hip_runtime.h>

// ---------------- bf16 helpers (raw ushort storage) ----------------
__device__ __forceinline__ float b2f(unsigned short u) {
    union { unsigned int i; float f; } x; x.i = ((unsigned int)u) << 16; return x.f;
}
__device__ __forceinline__ unsigned short f2b(float f) {
    union { float f; unsigned int i; } x; x.f = f;
    unsigned int r = x.i + 0x7fffu + ((x.i >> 16) & 1u);   // RNE
    return (unsigned short)(r >> 16);
}
__device__ __forceinline__ bool finitef(float x) {
    union { float f; unsigned int u; } c; c.f = x;
    return ((c.u >> 23) & 0xffu) != 0xffu;
}

typedef __attribute__((ext_vector_type(8))) __bf16 bf16x8;
typedef __attribute__((ext_vector_type(4))) float f32x4;

#define HDIM 128
#define LSTR 136
// Fused adjacency row: one 128B cache line per node = [int cnt | 62 x ushort adj].
#define ROWU 64    // ushorts per row (128B)
#define DCAP 62    // adjacency capacity
// BN stats shadow copies (32x less atomic contention; consumers sum copies).
#define NCOPY 32
// Session ledger: R1 shadow-copy stats atomics (+69us). R2: 64B-granularity gathers
// regress - keep 256B node-major rows. R3: scatter WRITE amp = device-atomic RMW
// (placement-invariant) -> R5 binned CSR build (+16us, scatter path retired).
// R6: dual-node MLP alone regressed (latency path saturated ~32 lines/wave, VGPR up).
// R7: half-split+XCD-pin cut misses 38% (FETCH 80->58MB) but halved concurrency ->
// slower. OPEN (R8, unmeasured due to broker outage): dual-node x half-split
// synthesis predicted ~33-38us/agg. This source = best MEASURED state (R5, 240us).
#define NB 256      // dst-range buckets
#define BCAP 8192   // edges per bucket capacity (mean E/NB ~ 3.1k; binomial tail ~0)

// BN scale/shift from per-column shadow-copy sums (computed redundantly per consumer block)
__device__ __forceinline__ void bn_compute(const float* colsum, const float* colsq,
                                           const unsigned short* gam, const unsigned short* bet,
                                           int isbf, float invn, int f,
                                           float* sc_out, float* sf_out) {
    float cs = 0.f, cq = 0.f;
#pragma unroll
    for (int c = 0; c < NCOPY; ++c) {
        cs += colsum[c * 128 + f];
        cq += colsq[c * 128 + f];
    }
    float gv, bv;
    if (isbf) { gv = b2f(gam[f]);            bv = b2f(bet[f]); }
    else      { gv = ((const float*)gam)[f]; bv = ((const float*)bet)[f]; }
    if (!finitef(cs) || !finitef(cq)) { *sc_out = 0.f; *sf_out = 150.f; return; }
    float mu = cs * invn;
    float var = cq * invn - mu * mu;
    var = var < 0.f ? 0.f : var;
    float rstd = rsqrtf(var + 1e-5f);
    float s = gv * rstd;
    *sc_out = s;
    *sf_out = bv - mu * s;
}

// ---------------- failure-path fill ----------------
__global__ void fill_f32(float* p, int n, float v) {
    int i = blockIdx.x * 256 + threadIdx.x;
    if (i < n) p[i] = v;
}

// ---------------- prep: dtype+is64 detect, W transpose, zero stats+bucketCnt ----------------
__global__ void prep(const unsigned short* __restrict__ X0, const int* __restrict__ ei,
                     const unsigned short* __restrict__ W1, const unsigned short* __restrict__ W2,
                     unsigned short* __restrict__ Wt1, unsigned short* __restrict__ Wt2,
                     int* __restrict__ zbase, int zcount, int* __restrict__ flags) {
    int bid = blockIdx.x, tid = threadIdx.x;
    if (bid < 128) {
        __shared__ int sane, hi64;
        if (tid == 0) { sane = 0; hi64 = 0; }
        __syncthreads();
        unsigned short u = X0[2 * tid];
        int e = (u >> 7) & 0xff;
        if (e >= 100 && e <= 140) atomicAdd(&sane, 1);
        if (bid == 0 && tid < 64) {          // int64 edges => high words all zero
            if (ei[2 * tid + 1] != 0) atomicAdd(&hi64, 1);
        }
        __syncthreads();
        int isbf = (sane >= 128) ? 1 : 0;
        if (bid == 0 && tid == 0) { flags[0] = isbf; flags[1] = (hi64 == 0) ? 1 : 0; }
        int idx = bid * 256 + tid;           // 0..32767
        const unsigned short* src; unsigned short* dst; int l;
        if (idx < 16384) { src = W1; dst = Wt1; l = idx; }
        else             { src = W2; dst = Wt2; l = idx - 16384; }
        int k = l >> 7, c = l & 127;
        unsigned short v = isbf ? src[l] : f2b(((const float*)src)[l]);
        dst[c * 128 + k] = v;                // Wt[n][k]
    } else {
        int i = (bid - 128) * 256 + tid;
        if (i < zcount) zbase[i] = 0;
    }
}

// ---------------- Phase A: bin edges by dst range, aggregated slot-claims ----------------
// 4096 edges/block. LDS histogram over NB buckets -> one global atomicAdd per
// (block,bucket) reserves a contiguous run; packed (src | dstloc<<16) u32 written there.
__global__ __launch_bounds__(256) void bin_edges(const int* __restrict__ ei,
                                                 unsigned int* __restrict__ bData,
                                                 unsigned int* __restrict__ bCnt,
                                                 const int* __restrict__ flags,
                                                 int E, int N, int BSZ) {
    __shared__ unsigned int cnt[NB];
    __shared__ unsigned int base[NB];
    int tid = threadIdx.x;
    int is64 = flags[1];
    int e0 = blockIdx.x * 4096;
    cnt[tid] = 0;                            // blockDim == NB == 256
    __syncthreads();
    unsigned int val[16], loff[16]; int bk[16];
#pragma unroll
    for (int j = 0; j < 16; ++j) {
        int e = e0 + j * 256 + tid;
        bk[j] = -1;
        if (e < E) {
            int d, s;
            if (is64) { d = ei[2 * (size_t)E + 2 * (size_t)e]; s = ei[2 * (size_t)e]; }
            else      { d = ei[(size_t)E + e];                 s = ei[e]; }
            d = d < 0 ? 0 : (d >= N ? N - 1 : d);
            s = s < 0 ? 0 : (s >= N ? N - 1 : s);
            int b = d / BSZ;
            int loc = d - b * BSZ;           // < BSZ <= 256
            val[j] = (unsigned int)s | ((unsigned int)loc << 16);
            bk[j] = b;
            loff[j] = atomicAdd(&cnt[b], 1u);
        }
    }
    __syncthreads();
    unsigned int c = cnt[tid];
    base[tid] = (c > 0) ? atomicAdd(&bCnt[tid], c) : 0u;   // bucket tid
    __syncthreads();
#pragma unroll
    for (int j = 0; j < 16; ++j) {
        if (bk[j] >= 0) {
            unsigned int pos = base[bk[j]] + loff[j];
            if (pos < BCAP) bData[(size_t)bk[j] * BCAP + pos] = val[j];
        }
    }
}

// ---------------- Phase B: build csr rows in LDS, stream out full lines ----------------
__global__ __launch_bounds__(256) void build_csr(const unsigned int* __restrict__ bData,
                                                 const unsigned int* __restrict__ bCnt,
                                                 unsigned short* __restrict__ csr2d,
                                                 int N, int BSZ) {
    __shared__ __align__(16) unsigned short rows[256 * ROWU];   // 32KB
    int b = blockIdx.x;
    int tid = threadIdx.x;
    int node0 = b * BSZ;
    int nn = N - node0; if (nn > BSZ) nn = BSZ;
    if (nn <= 0) return;
    uint4* r4 = (uint4*)rows;
#pragma unroll
    for (int i = 0; i < 8; ++i) { uint4 z = {0u, 0u, 0u, 0u}; r4[tid + i * 256] = z; }
    __syncthreads();
    unsigned int ne = bCnt[b]; if (ne > BCAP) ne = BCAP;
    const unsigned int* bd = &bData[(size_t)b * BCAP];
    for (unsigned int t = tid; t < ne; t += 256) {
        unsigned int v = bd[t];
        unsigned int loc = v >> 16;
        unsigned int s = v & 0xffffu;
        unsigned int c = atomicAdd((unsigned int*)&rows[loc * ROWU], 1u);
        if (c < DCAP) rows[loc * ROWU + 2 + c] = (unsigned short)s;
    }
    __syncthreads();
    uint4* g4 = (uint4*)&csr2d[(size_t)node0 * ROWU];
    int tot = nn * (ROWU / 8);
    for (int i = tid; i < tot; i += 256) g4[i] = r4[i];
}

// ---------------- GEMM (MFMA 16x16x32 bf16): C[n,128] = dinv[n] * (A[n,128] @ W) ----------------
__global__ __launch_bounds__(256) void gemm_mfma(
    const unsigned short* __restrict__ A, const unsigned short* __restrict__ Wt,
    unsigned short* __restrict__ C, const int* __restrict__ aflag, int mode,
    const float* __restrict__ colsum, const float* __restrict__ colsq,
    const unsigned short* __restrict__ gam, const unsigned short* __restrict__ bet,
    float invn, const unsigned short* __restrict__ csr2d, int n) {
    __shared__ __align__(16) unsigned short Wl[128 * LSTR];
    __shared__ __align__(16) unsigned short Al[64 * LSTR];
    __shared__ float sc_sh[128], sf_sh[128];
    int tid = threadIdx.x;
    int row0 = blockIdx.x * 64;
    int isbf = aflag[0];

    if (mode == 2 && tid < 128)
        bn_compute(colsum, colsq, gam, bet, isbf, invn, tid, &sc_sh[tid], &sf_sh[tid]);

    const uint4* Wg = (const uint4*)Wt;
#pragma unroll
    for (int it = 0; it < 8; ++it) {
        int idx = tid + it * 256;
        int nn = idx >> 4, k8 = idx & 15;
        *(uint4*)&Wl[nn * LSTR + k8 * 8] = Wg[idx];
    }
    if (mode == 2) __syncthreads();   // sc_sh/sf_sh ready before A staging

    int amode = (mode == 2) ? 2 : isbf;
    if (amode == 1) {
        const uint4* Ag = (const uint4*)A;
        for (int it = 0; it < 4; ++it) {
            int idx = tid + it * 256;
            int r = idx >> 4, cc = idx & 15;
            int gr = row0 + r;
            uint4 v; v.x = v.y = v.z = v.w = 0u;
            if (gr < n) v = Ag[(size_t)gr * 16 + cc];
            *(uint4*)&Al[r * LSTR + cc * 8] = v;
        }
    } else if (amode == 0) {
        const uint4* Af = (const uint4*)A;
        for (int it = 0; it < 8; ++it) {
            int idx = tid + it * 256;
            int r = idx >> 5, c4 = idx & 31;
            int gr = row0 + r;
            uint4 v; v.x = v.y = v.z = v.w = 0u;
            if (gr < n) v = Af[(size_t)gr * 32 + c4];
            float ff[4]; *(uint4*)ff = v;
            ushort4 o;
            o.x = f2b(ff[0]); o.y = f2b(ff[1]); o.z = f2b(ff[2]); o.w = f2b(ff[3]);
            *(ushort4*)&Al[r * LSTR + c4 * 4] = o;
        }
    } else {                   // AGG bf16 + fused BN + ReLU (from sc_sh/sf_sh)
        const uint4* Ag = (const uint4*)A;
        for (int it = 0; it < 4; ++it) {
            int idx = tid + it * 256;
            int r = idx >> 4, cc = idx & 15;
            int gr = row0 + r;
            uint4 v; v.x = v.y = v.z = v.w = 0u;
            if (gr < n) v = Ag[(size_t)gr * 16 + cc];
            unsigned short hu[8]; *(uint4*)hu = v;
            unsigned short ou[8];
#pragma unroll
            for (int j = 0; j < 8; ++j) {
                int f = cc * 8 + j;
                float x = b2f(hu[j]) * sc_sh[f] + sf_sh[f];
                ou[j] = f2b(x > 0.f ? x : 0.f);
            }
            *(uint4*)&Al[r * LSTR + cc * 8] = *(uint4*)ou;
        }
    }
    __syncthreads();

    int wave = tid >> 6, lane = tid & 63;
    int m = lane & 15, quad = lane >> 4;

    bf16x8 afr[4];
#pragma unroll
    for (int kc = 0; kc < 4; ++kc)
        afr[kc] = *(const bf16x8*)&Al[(wave * 16 + m) * LSTR + kc * 32 + quad * 8];

    float dv[4];
#pragma unroll
    for (int i2 = 0; i2 < 4; ++i2) {
        int gr = row0 + wave * 16 + quad * 4 + i2;
        if (gr < n) {
            int ct = *(const int*)&csr2d[(size_t)gr * ROWU];
            dv[i2] = rsqrtf((float)ct + 1.0f);
        } else dv[i2] = 0.f;
    }

    for (int t = 0; t < 8; ++t) {
        f32x4 acc = {0.f, 0.f, 0.f, 0.f};
#pragma unroll
        for (int kc = 0; kc < 4; ++kc) {
            bf16x8 bfr = *(const bf16x8*)&Wl[(t * 16 + m) * LSTR + kc * 32 + quad * 8];
            acc = __builtin_amdgcn_mfma_f32_16x16x32_bf16(afr[kc], bfr, acc, 0, 0, 0);
        }
#pragma unroll
        for (int i2 = 0; i2 < 4; ++i2) {
            int gr = row0 + wave * 16 + quad * 4 + i2;
            if (gr < n) C[(size_t)gr * 128 + t * 16 + m] = f2b(acc[i2] * dv[i2]);
        }
    }
}

// ---------------- aggregation + fused BN column stats (shadow-copy atomics) ----------------
__global__ __launch_bounds__(256) void agg_stats(
    const unsigned short* __restrict__ Hb, const unsigned short* __restrict__ csr2d,
    unsigned short* __restrict__ AGG,
    float* __restrict__ colsum, float* __restrict__ colsq, int n) {
    int tid = threadIdx.x;
    int wave = tid >> 6, lane = tid & 63;
    int g = lane >> 4, q = lane & 15;

    float s1[8], s2[8];
#pragma unroll
    for (int j = 0; j < 8; ++j) { s1[j] = 0.f; s2[j] = 0.f; }

    for (int i = blockIdx.x * 4 + wave; i < n; i += gridDim.x * 4) {
        const unsigned short* row = &csr2d[(size_t)i * ROWU];
        int ct = *(const int*)row;
        float di = rsqrtf((float)ct + 1.0f);
        int c = ct < DCAP ? ct : DCAP;
        const unsigned short* adj = row + 2;
        float acc[8];
#pragma unroll
        for (int j = 0; j < 8; ++j) acc[j] = 0.f;

        if (g == 0) {   // self-loop (pre-scaled row)
            uint4 a4 = *(const uint4*)&Hb[(size_t)i * 128 + q * 8];
            unsigned short au[8]; *(uint4*)au = a4;
#pragma unroll
            for (int j = 0; j < 8; ++j) acc[j] += b2f(au[j]);
        }

        int t = g;
        for (; t + 12 < c; t += 16) {            // 4 independent gather chains
            int sA = adj[t];
            int sB = adj[t + 4];
            int sC = adj[t + 8];
            int sD = adj[t + 12];
            uint4 a4 = *(const uint4*)&Hb[(size_t)sA * 128 + q * 8];
            uint4 b4 = *(const uint4*)&Hb[(size_t)sB * 128 + q * 8];
            uint4 c4 = *(const uint4*)&Hb[(size_t)sC * 128 + q * 8];
            uint4 d4 = *(const uint4*)&Hb[(size_t)sD * 128 + q * 8];
            unsigned short au[8]; *(uint4*)au = a4;
            unsigned short bu[8]; *(uint4*)bu = b4;
            unsigned short cu[8]; *(uint4*)cu = c4;
            unsigned short du[8]; *(uint4*)du = d4;
#pragma unroll
            for (int j = 0; j < 8; ++j)
                acc[j] += (b2f(au[j]) + b2f(bu[j])) + (b2f(cu[j]) + b2f(du[j]));
        }
        for (; t < c; t += 4) {
            int sA = adj[t];
            uint4 a4 = *(const uint4*)&Hb[(size_t)sA * 128 + q * 8];
            unsigned short au[8]; *(uint4*)au = a4;
#pragma unroll
            for (int j = 0; j < 8; ++j) acc[j] += b2f(au[j]);
        }

#pragma unroll
        for (int j = 0; j < 8; ++j) {
            acc[j] += __shfl_xor(acc[j], 16, 64);
            acc[j] += __shfl_xor(acc[j], 32, 64);
            acc[j] *= di;
        }
        if (g == 0) {
            unsigned short ou[8];
#pragma unroll
            for (int j = 0; j < 8; ++j) {
                float v = acc[j];
                ou[j] = f2b(v);
                s1[j] += v; s2[j] += v * v;
            }
            *(uint4*)&AGG[(size_t)i * 128 + q * 8] = *(uint4*)ou;
        }
    }

    __shared__ float sh[4][256];
    if (g == 0) {
#pragma unroll
        for (int j = 0; j < 8; ++j) {
            sh[wave][q * 8 + j] = s1[j];
            sh[wave][128 + q * 8 + j] = s2[j];
        }
    }
    __syncthreads();
    if (tid < 128) {
        float a = sh[0][tid] + sh[1][tid] + sh[2][tid] + sh[3][tid];
        float b = sh[0][128 + tid] + sh[1][128 + tid] + sh[2][128 + tid] + sh[3][128 + tid];
        int copy = blockIdx.x & (NCOPY - 1);
        atomicAdd(&colsum[copy * 128 + tid], a);
        atomicAdd(&colsq[copy * 128 + tid], b);
    }
}

// ---------------- final: compute BN per-block + apply + ReLU to fp32 d_out ----------------
__global__ void bn_apply_f32(const unsigned short* __restrict__ AGG,
                             const float* __restrict__ colsum, const float* __restrict__ colsq,
                             const unsigned short* __restrict__ gam, const unsigned short* __restrict__ bet,
                             const int* __restrict__ flag, float invn,
                             float* __restrict__ out, int nchunk) {
    __shared__ float sc_sh[128], sf_sh[128];
    int tid = threadIdx.x;
    if (tid < 128)
        bn_compute(colsum, colsq, gam, bet, flag[0], invn, tid, &sc_sh[tid], &sf_sh[tid]);
    __syncthreads();
    int i = blockIdx.x * 256 + tid;
    if (i >= nchunk) return;
    int base = i * 8;
    int f0 = base & 127;
    uint4 hv = *(const uint4*)&AGG[base];
    unsigned short hu[8]; *(uint4*)hu = hv;
    float o[8];
#pragma unroll
    for (int j = 0; j < 8; ++j) {
        float v = b2f(hu[j]) * sc_sh[f0 + j] + sf_sh[f0 + j];
        o[j] = v > 0.f ? v : 0.f;
    }
    *(float4*)&out[base] = *(float4*)&o[0];
    *(float4*)&out[base + 4] = *(float4*)&o[4];
}

// ---------------- launch ----------------
extern "C" void kernel_launch(void* const* d_in, const int* in_sizes, int n_in,
                              void* d_out, int out_size, void* d_ws, size_t ws_size,
                              hipStream_t stream) {
    const unsigned short* X0 = (const unsigned short*)d_in[0];
    const int* ei = (const int*)d_in[1];
    const unsigned short* W1 = (const unsigned short*)d_in[2];
    const unsigned short* W2 = (const unsigned short*)d_in[4];
    const unsigned short* g1 = (const unsigned short*)d_in[6];
    const unsigned short* be1 = (const unsigned short*)d_in[7];
    const unsigned short* g2 = (const unsigned short*)d_in[8];
    const unsigned short* be2 = (const unsigned short*)d_in[9];
    float* OUT = (float*)d_out;

    int N = in_sizes[0] / HDIM;
    int E = in_sizes[1] / 2;
    int total = N * HDIM;
    int applyb = (total + 255) / 256;

    bool ok = (n_in == 10) && (N > 0) && (in_sizes[0] == N * HDIM) && (E > 0)
           && (in_sizes[2] == HDIM * HDIM) && (in_sizes[4] == HDIM * HDIM)
           && (in_sizes[6] == HDIM) && (in_sizes[9] == HDIM) && (out_size == total)
           && (N <= 65536);
    if (!ok) { fill_f32<<<applyb, 256, 0, stream>>>(OUT, total, -100.0f); return; }

    size_t need = 1024 + (size_t)N * ROWU * 2 + (size_t)NCOPY * 512 * 4 + NB * 4 + 64
                + (size_t)total * 4 + 65536 + (size_t)NB * BCAP * 4 + 4096;
    if (ws_size < need) { fill_f32<<<applyb, 256, 0, stream>>>(OUT, total, -300.0f); return; }

    char* w = (char*)d_ws;
    w = (char*)(((uintptr_t)w + 255) & ~(uintptr_t)255);
    unsigned short* csr2d = (unsigned short*)w; w += (size_t)N * ROWU * 2;
    float* stats = (float*)w; w += (size_t)NCOPY * 512 * 4;  // [zero region start]
    unsigned int* bCnt = (unsigned int*)w; w += NB * 4;      // [zero region end]
    int* flags = (int*)w;     w += 64;                       // written by prep (NOT zeroed)
    w = (char*)(((uintptr_t)w + 255) & ~(uintptr_t)255);
    unsigned short* Hb = (unsigned short*)w;  w += (size_t)total * 2;
    unsigned short* AGG = (unsigned short*)w; w += (size_t)total * 2;
    unsigned short* Wt1 = (unsigned short*)w; w += (size_t)HDIM * HDIM * 2;
    unsigned short* Wt2 = (unsigned short*)w; w += (size_t)HDIM * HDIM * 2;
    w = (char*)(((uintptr_t)w + 255) & ~(uintptr_t)255);
    unsigned int* bData = (unsigned int*)w; w += (size_t)NB * BCAP * 4;

    float* colsum1 = stats;
    float* colsq1 = stats + NCOPY * 128;
    float* colsum2 = stats + 2 * NCOPY * 128;
    float* colsq2 = stats + 3 * NCOPY * 128;

    int gemmb = (N + 63) / 64;
    float invn = 1.0f / (float)N;
    int BSZ = (N + NB - 1) / NB;                        // <= 256 given N <= 65536
    int zcount = NCOPY * 512 + NB;                      // stats floats + bucket counts

    prep<<<128 + (zcount + 255) / 256, 256, 0, stream>>>(X0, ei, W1, W2, Wt1, Wt2,
                                                         (int*)stats, zcount, flags);
    bin_edges<<<(E + 4095) / 4096, 256, 0, stream>>>(ei, bData, bCnt, flags, E, N, BSZ);
    build_csr<<<NB, 256, 0, stream>>>(bData, bCnt, csr2d, N, BSZ);

    // layer 1: Hb = dinv * (X @ W1)
    gemm_mfma<<<gemmb, 256, 0, stream>>>(X0, Wt1, Hb, flags, -1,
                                         nullptr, nullptr, nullptr, nullptr, invn, csr2d, N);
    agg_stats<<<2048, 256, 0, stream>>>(Hb, csr2d, AGG, colsum1, colsq1, N);

    // layer 2: BN(L1) + ReLU fused into gemm A-staging (BN computed per-block from colsum1)
    gemm_mfma<<<gemmb, 256, 0, stream>>>(AGG, Wt2, Hb, flags, 2,
                                         colsum1, colsq1, g1, be1, invn, csr2d, N);
    agg_stats<<<2048, 256, 0, stream>>>(Hb, csr2d, AGG, colsum2, colsq2, N);

    // final BN+ReLU (BN computed per-block from colsum2)
    bn_apply_f32<<<(total / 8 + 255) / 256, 256, 0, stream>>>(AGG, colsum2, colsq2,
                                                              g2, be2, flags, invn, OUT, total / 8);
}

// Round 20
// 238.492 us; speedup vs baseline: 1.1134x; 1.0002x over previous
//
#include <hip/hip_runtime.h>

// ---------------- bf16 helpers (raw ushort storage) ----------------
__device__ __forceinline__ float b2f(unsigned short u) {
    union { unsigned int i; float f; } x; x.i = ((unsigned int)u) << 16; return x.f;
}
__device__ __forceinline__ unsigned short f2b(float f) {
    union { float f; unsigned int i; } x; x.f = f;
    unsigned int r = x.i + 0x7fffu + ((x.i >> 16) & 1u);   // RNE
    return (unsigned short)(r >> 16);
}
__device__ __forceinline__ bool finitef(float x) {
    union { float f; unsigned int u; } c; c.f = x;
    return ((c.u >> 23) & 0xffu) != 0xffu;
}

typedef __attribute__((ext_vector_type(8))) __bf16 bf16x8;
typedef __attribute__((ext_vector_type(4))) float f32x4;

#define HDIM 128
#define LSTR 136
// Fused adjacency row: one 128B cache line per node = [int cnt | 62 x ushort adj].
#define ROWU 64    // ushorts per row (128B)
#define DCAP 62    // adjacency capacity
// BN stats shadow copies (32x less atomic contention; consumers sum copies).
#define NCOPY 32
// Session ledger: R1 shadow-copy stats atomics (+69us). R2: 64B-granularity gathers
// regress - keep 256B node-major rows. R3: scatter WRITE amp = device-atomic RMW
// (placement-invariant) -> R5 binned CSR build (+16us, scatter path retired).
// R6: dual-node MLP alone regressed (latency path saturated ~32 lines/wave).
// R7: half-split+XCD-pin cut misses 38% (FETCH 80->58MB) but halved concurrency ->
// slower. OPEN (R8, never measured - broker outage): dual-node x half-split
// synthesis, predicted agg 33-38us. This source = best MEASURED state
// (R5 240.3us, reproduced R14 238.5us).
#define NB 256      // dst-range buckets
#define BCAP 8192   // edges per bucket capacity (mean E/NB ~ 3.1k; binomial tail ~0)

// BN scale/shift from per-column shadow-copy sums (computed redundantly per consumer block)
__device__ __forceinline__ void bn_compute(const float* colsum, const float* colsq,
                                           const unsigned short* gam, const unsigned short* bet,
                                           int isbf, float invn, int f,
                                           float* sc_out, float* sf_out) {
    float cs = 0.f, cq = 0.f;
#pragma unroll
    for (int c = 0; c < NCOPY; ++c) {
        cs += colsum[c * 128 + f];
        cq += colsq[c * 128 + f];
    }
    float gv, bv;
    if (isbf) { gv = b2f(gam[f]);            bv = b2f(bet[f]); }
    else      { gv = ((const float*)gam)[f]; bv = ((const float*)bet)[f]; }
    if (!finitef(cs) || !finitef(cq)) { *sc_out = 0.f; *sf_out = 150.f; return; }
    float mu = cs * invn;
    float var = cq * invn - mu * mu;
    var = var < 0.f ? 0.f : var;
    float rstd = rsqrtf(var + 1e-5f);
    float s = gv * rstd;
    *sc_out = s;
    *sf_out = bv - mu * s;
}

// ---------------- failure-path fill ----------------
__global__ void fill_f32(float* p, int n, float v) {
    int i = blockIdx.x * 256 + threadIdx.x;
    if (i < n) p[i] = v;
}

// ---------------- prep: dtype+is64 detect, W transpose, zero stats+bucketCnt ----------------
__global__ void prep(const unsigned short* __restrict__ X0, const int* __restrict__ ei,
                     const unsigned short* __restrict__ W1, const unsigned short* __restrict__ W2,
                     unsigned short* __restrict__ Wt1, unsigned short* __restrict__ Wt2,
                     int* __restrict__ zbase, int zcount, int* __restrict__ flags) {
    int bid = blockIdx.x, tid = threadIdx.x;
    if (bid < 128) {
        __shared__ int sane, hi64;
        if (tid == 0) { sane = 0; hi64 = 0; }
        __syncthreads();
        unsigned short u = X0[2 * tid];
        int e = (u >> 7) & 0xff;
        if (e >= 100 && e <= 140) atomicAdd(&sane, 1);
        if (bid == 0 && tid < 64) {          // int64 edges => high words all zero
            if (ei[2 * tid + 1] != 0) atomicAdd(&hi64, 1);
        }
        __syncthreads();
        int isbf = (sane >= 128) ? 1 : 0;
        if (bid == 0 && tid == 0) { flags[0] = isbf; flags[1] = (hi64 == 0) ? 1 : 0; }
        int idx = bid * 256 + tid;           // 0..32767
        const unsigned short* src; unsigned short* dst; int l;
        if (idx < 16384) { src = W1; dst = Wt1; l = idx; }
        else             { src = W2; dst = Wt2; l = idx - 16384; }
        int k = l >> 7, c = l & 127;
        unsigned short v = isbf ? src[l] : f2b(((const float*)src)[l]);
        dst[c * 128 + k] = v;                // Wt[n][k]
    } else {
        int i = (bid - 128) * 256 + tid;
        if (i < zcount) zbase[i] = 0;
    }
}

// ---------------- Phase A: bin edges by dst range, aggregated slot-claims ----------------
// 4096 edges/block. LDS histogram over NB buckets -> one global atomicAdd per
// (block,bucket) reserves a contiguous run; packed (src | dstloc<<16) u32 written there.
__global__ __launch_bounds__(256) void bin_edges(const int* __restrict__ ei,
                                                 unsigned int* __restrict__ bData,
                                                 unsigned int* __restrict__ bCnt,
                                                 const int* __restrict__ flags,
                                                 int E, int N, int BSZ) {
    __shared__ unsigned int cnt[NB];
    __shared__ unsigned int base[NB];
    int tid = threadIdx.x;
    int is64 = flags[1];
    int e0 = blockIdx.x * 4096;
    cnt[tid] = 0;                            // blockDim == NB == 256
    __syncthreads();
    unsigned int val[16], loff[16]; int bk[16];
#pragma unroll
    for (int j = 0; j < 16; ++j) {
        int e = e0 + j * 256 + tid;
        bk[j] = -1;
        if (e < E) {
            int d, s;
            if (is64) { d = ei[2 * (size_t)E + 2 * (size_t)e]; s = ei[2 * (size_t)e]; }
            else      { d = ei[(size_t)E + e];                 s = ei[e]; }
            d = d < 0 ? 0 : (d >= N ? N - 1 : d);
            s = s < 0 ? 0 : (s >= N ? N - 1 : s);
            int b = d / BSZ;
            int loc = d - b * BSZ;           // < BSZ <= 256
            val[j] = (unsigned int)s | ((unsigned int)loc << 16);
            bk[j] = b;
            loff[j] = atomicAdd(&cnt[b], 1u);
        }
    }
    __syncthreads();
    unsigned int c = cnt[tid];
    base[tid] = (c > 0) ? atomicAdd(&bCnt[tid], c) : 0u;   // bucket tid
    __syncthreads();
#pragma unroll
    for (int j = 0; j < 16; ++j) {
        if (bk[j] >= 0) {
            unsigned int pos = base[bk[j]] + loff[j];
            if (pos < BCAP) bData[(size_t)bk[j] * BCAP + pos] = val[j];
        }
    }
}

// ---------------- Phase B: build csr rows in LDS, stream out full lines ----------------
__global__ __launch_bounds__(256) void build_csr(const unsigned int* __restrict__ bData,
                                                 const unsigned int* __restrict__ bCnt,
                                                 unsigned short* __restrict__ csr2d,
                                                 int N, int BSZ) {
    __shared__ __align__(16) unsigned short rows[256 * ROWU];   // 32KB
    int b = blockIdx.x;
    int tid = threadIdx.x;
    int node0 = b * BSZ;
    int nn = N - node0; if (nn > BSZ) nn = BSZ;
    if (nn <= 0) return;
    uint4* r4 = (uint4*)rows;
#pragma unroll
    for (int i = 0; i < 8; ++i) { uint4 z = {0u, 0u, 0u, 0u}; r4[tid + i * 256] = z; }
    __syncthreads();
    unsigned int ne = bCnt[b]; if (ne > BCAP) ne = BCAP;
    const unsigned int* bd = &bData[(size_t)b * BCAP];
    for (unsigned int t = tid; t < ne; t += 256) {
        unsigned int v = bd[t];
        unsigned int loc = v >> 16;
        unsigned int s = v & 0xffffu;
        unsigned int c = atomicAdd((unsigned int*)&rows[loc * ROWU], 1u);
        if (c < DCAP) rows[loc * ROWU + 2 + c] = (unsigned short)s;
    }
    __syncthreads();
    uint4* g4 = (uint4*)&csr2d[(size_t)node0 * ROWU];
    int tot = nn * (ROWU / 8);
    for (int i = tid; i < tot; i += 256) g4[i] = r4[i];
}

// ---------------- GEMM (MFMA 16x16x32 bf16): C[n,128] = dinv[n] * (A[n,128] @ W) ----------------
__global__ __launch_bounds__(256) void gemm_mfma(
    const unsigned short* __restrict__ A, const unsigned short* __restrict__ Wt,
    unsigned short* __restrict__ C, const int* __restrict__ aflag, int mode,
    const float* __restrict__ colsum, const float* __restrict__ colsq,
    const unsigned short* __restrict__ gam, const unsigned short* __restrict__ bet,
    float invn, const unsigned short* __restrict__ csr2d, int n) {
    __shared__ __align__(16) unsigned short Wl[128 * LSTR];
    __shared__ __align__(16) unsigned short Al[64 * LSTR];
    __shared__ float sc_sh[128], sf_sh[128];
    int tid = threadIdx.x;
    int row0 = blockIdx.x * 64;
    int isbf = aflag[0];

    if (mode == 2 && tid < 128)
        bn_compute(colsum, colsq, gam, bet, isbf, invn, tid, &sc_sh[tid], &sf_sh[tid]);

    const uint4* Wg = (const uint4*)Wt;
#pragma unroll
    for (int it = 0; it < 8; ++it) {
        int idx = tid + it * 256;
        int nn = idx >> 4, k8 = idx & 15;
        *(uint4*)&Wl[nn * LSTR + k8 * 8] = Wg[idx];
    }
    if (mode == 2) __syncthreads();   // sc_sh/sf_sh ready before A staging

    int amode = (mode == 2) ? 2 : isbf;
    if (amode == 1) {
        const uint4* Ag = (const uint4*)A;
        for (int it = 0; it < 4; ++it) {
            int idx = tid + it * 256;
            int r = idx >> 4, cc = idx & 15;
            int gr = row0 + r;
            uint4 v; v.x = v.y = v.z = v.w = 0u;
            if (gr < n) v = Ag[(size_t)gr * 16 + cc];
            *(uint4*)&Al[r * LSTR + cc * 8] = v;
        }
    } else if (amode == 0) {
        const uint4* Af = (const uint4*)A;
        for (int it = 0; it < 8; ++it) {
            int idx = tid + it * 256;
            int r = idx >> 5, c4 = idx & 31;
            int gr = row0 + r;
            uint4 v; v.x = v.y = v.z = v.w = 0u;
            if (gr < n) v = Af[(size_t)gr * 32 + c4];
            float ff[4]; *(uint4*)ff = v;
            ushort4 o;
            o.x = f2b(ff[0]); o.y = f2b(ff[1]); o.z = f2b(ff[2]); o.w = f2b(ff[3]);
            *(ushort4*)&Al[r * LSTR + c4 * 4] = o;
        }
    } else {                   // AGG bf16 + fused BN + ReLU (from sc_sh/sf_sh)
        const uint4* Ag = (const uint4*)A;
        for (int it = 0; it < 4; ++it) {
            int idx = tid + it * 256;
            int r = idx >> 4, cc = idx & 15;
            int gr = row0 + r;
            uint4 v; v.x = v.y = v.z = v.w = 0u;
            if (gr < n) v = Ag[(size_t)gr * 16 + cc];
            unsigned short hu[8]; *(uint4*)hu = v;
            unsigned short ou[8];
#pragma unroll
            for (int j = 0; j < 8; ++j) {
                int f = cc * 8 + j;
                float x = b2f(hu[j]) * sc_sh[f] + sf_sh[f];
                ou[j] = f2b(x > 0.f ? x : 0.f);
            }
            *(uint4*)&Al[r * LSTR + cc * 8] = *(uint4*)ou;
        }
    }
    __syncthreads();

    int wave = tid >> 6, lane = tid & 63;
    int m = lane & 15, quad = lane >> 4;

    bf16x8 afr[4];
#pragma unroll
    for (int kc = 0; kc < 4; ++kc)
        afr[kc] = *(const bf16x8*)&Al[(wave * 16 + m) * LSTR + kc * 32 + quad * 8];

    float dv[4];
#pragma unroll
    for (int i2 = 0; i2 < 4; ++i2) {
        int gr = row0 + wave * 16 + quad * 4 + i2;
        if (gr < n) {
            int ct = *(const int*)&csr2d[(size_t)gr * ROWU];
            dv[i2] = rsqrtf((float)ct + 1.0f);
        } else dv[i2] = 0.f;
    }

    for (int t = 0; t < 8; ++t) {
        f32x4 acc = {0.f, 0.f, 0.f, 0.f};
#pragma unroll
        for (int kc = 0; kc < 4; ++kc) {
            bf16x8 bfr = *(const bf16x8*)&Wl[(t * 16 + m) * LSTR + kc * 32 + quad * 8];
            acc = __builtin_amdgcn_mfma_f32_16x16x32_bf16(afr[kc], bfr, acc, 0, 0, 0);
        }
#pragma unroll
        for (int i2 = 0; i2 < 4; ++i2) {
            int gr = row0 + wave * 16 + quad * 4 + i2;
            if (gr < n) C[(size_t)gr * 128 + t * 16 + m] = f2b(acc[i2] * dv[i2]);
        }
    }
}

// ---------------- aggregation + fused BN column stats (shadow-copy atomics) ----------------
__global__ __launch_bounds__(256) void agg_stats(
    const unsigned short* __restrict__ Hb, const unsigned short* __restrict__ csr2d,
    unsigned short* __restrict__ AGG,
    float* __restrict__ colsum, float* __restrict__ colsq, int n) {
    int tid = threadIdx.x;
    int wave = tid >> 6, lane = tid & 63;
    int g = lane >> 4, q = lane & 15;

    float s1[8], s2[8];
#pragma unroll
    for (int j = 0; j < 8; ++j) { s1[j] = 0.f; s2[j] = 0.f; }

    for (int i = blockIdx.x * 4 + wave; i < n; i += gridDim.x * 4) {
        const unsigned short* row = &csr2d[(size_t)i * ROWU];
        int ct = *(const int*)row;
        float di = rsqrtf((float)ct + 1.0f);
        int c = ct < DCAP ? ct : DCAP;
        const unsigned short* adj = row + 2;
        float acc[8];
#pragma unroll
        for (int j = 0; j < 8; ++j) acc[j] = 0.f;

        if (g == 0) {   // self-loop (pre-scaled row)
            uint4 a4 = *(const uint4*)&Hb[(size_t)i * 128 + q * 8];
            unsigned short au[8]; *(uint4*)au = a4;
#pragma unroll
            for (int j = 0; j < 8; ++j) acc[j] += b2f(au[j]);
        }

        int t = g;
        for (; t + 12 < c; t += 16) {            // 4 independent gather chains
            int sA = adj[t];
            int sB = adj[t + 4];
            int sC = adj[t + 8];
            int sD = adj[t + 12];
            uint4 a4 = *(const uint4*)&Hb[(size_t)sA * 128 + q * 8];
            uint4 b4 = *(const uint4*)&Hb[(size_t)sB * 128 + q * 8];
            uint4 c4 = *(const uint4*)&Hb[(size_t)sC * 128 + q * 8];
            uint4 d4 = *(const uint4*)&Hb[(size_t)sD * 128 + q * 8];
            unsigned short au[8]; *(uint4*)au = a4;
            unsigned short bu[8]; *(uint4*)bu = b4;
            unsigned short cu[8]; *(uint4*)cu = c4;
            unsigned short du[8]; *(uint4*)du = d4;
#pragma unroll
            for (int j = 0; j < 8; ++j)
                acc[j] += (b2f(au[j]) + b2f(bu[j])) + (b2f(cu[j]) + b2f(du[j]));
        }
        for (; t < c; t += 4) {
            int sA = adj[t];
            uint4 a4 = *(const uint4*)&Hb[(size_t)sA * 128 + q * 8];
            unsigned short au[8]; *(uint4*)au = a4;
#pragma unroll
            for (int j = 0; j < 8; ++j) acc[j] += b2f(au[j]);
        }

#pragma unroll
        for (int j = 0; j < 8; ++j) {
            acc[j] += __shfl_xor(acc[j], 16, 64);
            acc[j] += __shfl_xor(acc[j], 32, 64);
            acc[j] *= di;
        }
        if (g == 0) {
            unsigned short ou[8];
#pragma unroll
            for (int j = 0; j < 8; ++j) {
                float v = acc[j];
                ou[j] = f2b(v);
                s1[j] += v; s2[j] += v * v;
            }
            *(uint4*)&AGG[(size_t)i * 128 + q * 8] = *(uint4*)ou;
        }
    }

    __shared__ float sh[4][256];
    if (g == 0) {
#pragma unroll
        for (int j = 0; j < 8; ++j) {
            sh[wave][q * 8 + j] = s1[j];
            sh[wave][128 + q * 8 + j] = s2[j];
        }
    }
    __syncthreads();
    if (tid < 128) {
        float a = sh[0][tid] + sh[1][tid] + sh[2][tid] + sh[3][tid];
        float b = sh[0][128 + tid] + sh[1][128 + tid] + sh[2][128 + tid] + sh[3][128 + tid];
        int copy = blockIdx.x & (NCOPY - 1);
        atomicAdd(&colsum[copy * 128 + tid], a);
        atomicAdd(&colsq[copy * 128 + tid], b);
    }
}

// ---------------- final: compute BN per-block + apply + ReLU to fp32 d_out ----------------
__global__ void bn_apply_f32(const unsigned short* __restrict__ AGG,
                             const float* __restrict__ colsum, const float* __restrict__ colsq,
                             const unsigned short* __restrict__ gam, const unsigned short* __restrict__ bet,
                             const int* __restrict__ flag, float invn,
                             float* __restrict__ out, int nchunk) {
    __shared__ float sc_sh[128], sf_sh[128];
    int tid = threadIdx.x;
    if (tid < 128)
        bn_compute(colsum, colsq, gam, bet, flag[0], invn, tid, &sc_sh[tid], &sf_sh[tid]);
    __syncthreads();
    int i = blockIdx.x * 256 + tid;
    if (i >= nchunk) return;
    int base = i * 8;
    int f0 = base & 127;
    uint4 hv = *(const uint4*)&AGG[base];
    unsigned short hu[8]; *(uint4*)hu = hv;
    float o[8];
#pragma unroll
    for (int j = 0; j < 8; ++j) {
        float v = b2f(hu[j]) * sc_sh[f0 + j] + sf_sh[f0 + j];
        o[j] = v > 0.f ? v : 0.f;
    }
    *(float4*)&out[base] = *(float4*)&o[0];
    *(float4*)&out[base + 4] = *(float4*)&o[4];
}

// ---------------- launch ----------------
extern "C" void kernel_launch(void* const* d_in, const int* in_sizes, int n_in,
                              void* d_out, int out_size, void* d_ws, size_t ws_size,
                              hipStream_t stream) {
    const unsigned short* X0 = (const unsigned short*)d_in[0];
    const int* ei = (const int*)d_in[1];
    const unsigned short* W1 = (const unsigned short*)d_in[2];
    const unsigned short* W2 = (const unsigned short*)d_in[4];
    const unsigned short* g1 = (const unsigned short*)d_in[6];
    const unsigned short* be1 = (const unsigned short*)d_in[7];
    const unsigned short* g2 = (const unsigned short*)d_in[8];
    const unsigned short* be2 = (const unsigned short*)d_in[9];
    float* OUT = (float*)d_out;

    int N = in_sizes[0] / HDIM;
    int E = in_sizes[1] / 2;
    int total = N * HDIM;
    int applyb = (total + 255) / 256;

    bool ok = (n_in == 10) && (N > 0) && (in_sizes[0] == N * HDIM) && (E > 0)
           && (in_sizes[2] == HDIM * HDIM) && (in_sizes[4] == HDIM * HDIM)
           && (in_sizes[6] == HDIM) && (in_sizes[9] == HDIM) && (out_size == total)
           && (N <= 65536);
    if (!ok) { fill_f32<<<applyb, 256, 0, stream>>>(OUT, total, -100.0f); return; }

    size_t need = 1024 + (size_t)N * ROWU * 2 + (size_t)NCOPY * 512 * 4 + NB * 4 + 64
                + (size_t)total * 4 + 65536 + (size_t)NB * BCAP * 4 + 4096;
    if (ws_size < need) { fill_f32<<<applyb, 256, 0, stream>>>(OUT, total, -300.0f); return; }

    char* w = (char*)d_ws;
    w = (char*)(((uintptr_t)w + 255) & ~(uintptr_t)255);
    unsigned short* csr2d = (unsigned short*)w; w += (size_t)N * ROWU * 2;
    float* stats = (float*)w; w += (size_t)NCOPY * 512 * 4;  // [zero region start]
    unsigned int* bCnt = (unsigned int*)w; w += NB * 4;      // [zero region end]
    int* flags = (int*)w;     w += 64;                       // written by prep (NOT zeroed)
    w = (char*)(((uintptr_t)w + 255) & ~(uintptr_t)255);
    unsigned short* Hb = (unsigned short*)w;  w += (size_t)total * 2;
    unsigned short* AGG = (unsigned short*)w; w += (size_t)total * 2;
    unsigned short* Wt1 = (unsigned short*)w; w += (size_t)HDIM * HDIM * 2;
    unsigned short* Wt2 = (unsigned short*)w; w += (size_t)HDIM * HDIM * 2;
    w = (char*)(((uintptr_t)w + 255) & ~(uintptr_t)255);
    unsigned int* bData = (unsigned int*)w; w += (size_t)NB * BCAP * 4;

    float* colsum1 = stats;
    float* colsq1 = stats + NCOPY * 128;
    float* colsum2 = stats + 2 * NCOPY * 128;
    float* colsq2 = stats + 3 * NCOPY * 128;

    int gemmb = (N + 63) / 64;
    float invn = 1.0f / (float)N;
    int BSZ = (N + NB - 1) / NB;                        // <= 256 given N <= 65536
    int zcount = NCOPY * 512 + NB;                      // stats floats + bucket counts

    prep<<<128 + (zcount + 255) / 256, 256, 0, stream>>>(X0, ei, W1, W2, Wt1, Wt2,
                                                         (int*)stats, zcount, flags);
    bin_edges<<<(E + 4095) / 4096, 256, 0, stream>>>(ei, bData, bCnt, flags, E, N, BSZ);
    build_csr<<<NB, 256, 0, stream>>>(bData, bCnt, csr2d, N, BSZ);

    // layer 1: Hb = dinv * (X @ W1)
    gemm_mfma<<<gemmb, 256, 0, stream>>>(X0, Wt1, Hb, flags, -1,
                                         nullptr, nullptr, nullptr, nullptr, invn, csr2d, N);
    agg_stats<<<2048, 256, 0, stream>>>(Hb, csr2d, AGG, colsum1, colsq1, N);

    // layer 2: BN(L1) + ReLU fused into gemm A-staging (BN computed per-block from colsum1)
    gemm_mfma<<<gemmb, 256, 0, stream>>>(AGG, Wt2, Hb, flags, 2,
                                         colsum1, colsq1, g1, be1, invn, csr2d, N);
    agg_stats<<<2048, 256, 0, stream>>>(Hb, csr2d, AGG, colsum2, colsq2, N);

    // final BN+ReLU (BN computed per-block from colsum2)
    bn_apply_f32<<<(total / 8 + 255) / 256, 256, 0, stream>>>(AGG, colsum2, colsq2,
                                                              g2, be2, flags, invn, OUT, total / 8);
}